// Round 1
// baseline (50.581 us; speedup 1.0000x reference)
//
#include <hip/hip_runtime.h>

#define KN      1024
#define FAN_IN  16
#define NSP     64
#define THRESH  12

__global__ __launch_bounds__(256) void decoder_kernel(
    const float* __restrict__ prev_outputs,      // [1024,64,64]
    const void*  __restrict__ prev_is_active,    // [1024] bool(1B) or int32 (sniffed)
    const int*   __restrict__ parent_indices,    // [1024,16]
    const float* __restrict__ Wt,                // [1024,16,3,3]
    const float* __restrict__ bias,              // [1024]
    float*       __restrict__ out)               // [1024*4096] then [1024] activity
{
    __shared__ float s_map[66 * 66];
    __shared__ float s_w[FAN_IN * 9];
    __shared__ int   s_pidx[FAN_IN];
    __shared__ int   s_cnt;

    const int k   = blockIdx.x;
    const int tid = threadIdx.x;

    // --- sniff flag encoding: numpy bool (1 byte) vs int32. Deterministic. ---
    bool bytemode = false;
    {
        const unsigned* f32v = (const unsigned*)prev_is_active;
        #pragma unroll
        for (int i = 0; i < 16; ++i)
            if (f32v[i] > 1u) bytemode = true;
    }

    if (tid == 0) s_cnt = 0;
    __syncthreads();

    if (tid < FAN_IN) {
        int p = parent_indices[k * FAN_IN + tid];
        s_pidx[tid] = p;
        int f;
        if (bytemode) f = ((const unsigned char*)prev_is_active)[p] ? 1 : 0;
        else          f = ((const int*)prev_is_active)[p] ? 1 : 0;
        atomicAdd(&s_cnt, f);
    }
    if (tid < FAN_IN * 9) s_w[tid] = Wt[k * FAN_IN * 9 + tid];

    // zero the whole LDS tile once (halo stays zero; interior overwritten per channel)
    for (int i = tid; i < 66 * 66; i += 256) s_map[i] = 0.0f;

    __syncthreads();

    const bool active = (s_cnt >= THRESH);
    if (tid == 0) out[(size_t)KN * NSP * NSP + k] = active ? 1.0f : 0.0f;

    const size_t obase = (size_t)k * NSP * NSP;

    if (!active) {
        float4 z = make_float4(0.f, 0.f, 0.f, 0.f);
        float4* o4 = (float4*)(out + obase);
        for (int i = tid; i < NSP * NSP / 4; i += 256) o4[i] = z;
        return;
    }

    const int col = tid & 63;          // output column owned by this thread
    const int r0  = (tid >> 6) << 4;   // first of 16 output rows

    float acc[16];
    #pragma unroll
    for (int i = 0; i < 16; ++i) acc[i] = 0.0f;

    for (int c = 0; c < FAN_IN; ++c) {
        __syncthreads();   // previous channel's readers done before overwrite
        const float4* src = (const float4*)(prev_outputs + (size_t)s_pidx[c] * (NSP * NSP));
        for (int i = tid; i < NSP * NSP / 4; i += 256) {
            float4 v = src[i];
            int idx = i * 4;
            int rr = idx >> 6, cc = idx & 63;
            float* d = &s_map[(rr + 1) * 66 + cc + 1];
            d[0] = v.x; d[1] = v.y; d[2] = v.z; d[3] = v.w;
        }
        __syncthreads();

        const float* wc = &s_w[c * 9];
        const float w00 = wc[0], w01 = wc[1], w02 = wc[2];
        const float w10 = wc[3], w11 = wc[4], w12 = wc[5];
        const float w20 = wc[6], w21 = wc[7], w22 = wc[8];

        // sliding 3x3 window down the column strip; all reads 2-way-bank-free
        const float* base = &s_map[r0 * 66 + col];
        float a0 = base[0],  a1 = base[1],  a2 = base[2];
        float b0 = base[66], b1 = base[67], b2 = base[68];
        #pragma unroll
        for (int rr = 0; rr < 16; ++rr) {
            const float* p2 = base + (rr + 2) * 66;
            float c0 = p2[0], c1 = p2[1], c2 = p2[2];
            acc[rr] += w00 * a0 + w01 * a1 + w02 * a2
                     + w10 * b0 + w11 * b1 + w12 * b2
                     + w20 * c0 + w21 * c1 + w22 * c2;
            a0 = b0; a1 = b1; a2 = b2;
            b0 = c0; b1 = c1; b2 = c2;
        }
    }

    const float bk = bias[k];
    #pragma unroll
    for (int rr = 0; rr < 16; ++rr) {
        out[obase + (size_t)(r0 + rr) * NSP + col] = tanhf(acc[rr] + bk);
    }
}

extern "C" void kernel_launch(void* const* d_in, const int* in_sizes, int n_in,
                              void* d_out, int out_size, void* d_ws, size_t ws_size,
                              hipStream_t stream) {
    const float* prev_outputs   = (const float*)d_in[0];
    const void*  prev_is_active = d_in[1];
    const int*   parent_indices = (const int*)d_in[2];
    const float* Wt             = (const float*)d_in[3];
    const float* bias           = (const float*)d_in[4];
    float*       out            = (float*)d_out;

    decoder_kernel<<<dim3(KN), dim3(256), 0, stream>>>(
        prev_outputs, prev_is_active, parent_indices, Wt, bias, out);
}

// Round 2
// 42.481 us; speedup vs baseline: 1.1907x; 1.1907x over previous
//
#include <hip/hip_runtime.h>

#define KN      1024
#define FAN_IN  16
#define NSP     64
#define THRESH  12

__device__ __forceinline__ float tanh_fast(float x) {
    float ax = fabsf(x);
    float e  = __expf(-2.0f * ax);                       // e^{-2|x|}, native v_exp
    float r  = 1.0f - 2.0f * e * __builtin_amdgcn_rcpf(1.0f + e);
    return copysignf(r, x);
}

__device__ __forceinline__ float2 fma2(float w, float2 v, float2 a) {
    a.x = fmaf(w, v.x, a.x);
    a.y = fmaf(w, v.y, a.y);
    return a;
}

// 2 blocks per node; each block: 256 threads = 4 waves, 32 output rows.
// Thread owns col (tid&63), 8 output rows r0..r0+7 packed as float2 pairs (r, r+4).
__global__ __launch_bounds__(256) void decoder_kernel(
    const float* __restrict__ prev_outputs,      // [1024,64,64]
    const void*  __restrict__ prev_is_active,    // [1024] bool(1B) or int32 (sniffed)
    const int*   __restrict__ parent_indices,    // [1024,16]
    const float* __restrict__ Wt,                // [1024,16,3,3]
    const float* __restrict__ bias,              // [1024]
    float*       __restrict__ out)               // [1024*4096] + [1024] activity
{
    const int bid  = blockIdx.x;
    const int k    = bid >> 1;           // node
    const int half = bid & 1;            // which 32-row half
    const int tid  = threadIdx.x;
    const int col  = tid & 63;
    const int rg   = tid >> 6;           // wave id = row group
    const int r0   = half * 32 + rg * 8; // first of 8 output rows

    // --- sniff flag encoding: numpy bool (1 byte) vs int32. Deterministic. ---
    bool bytemode = false;
    {
        const unsigned* sv = (const unsigned*)prev_is_active;
        #pragma unroll
        for (int i = 0; i < 16; ++i)
            if (sv[i] > 1u) bytemode = true;
    }

    // --- activity gate: all-uniform scalar work, no LDS ---
    int cnt = 0;
    #pragma unroll
    for (int i = 0; i < FAN_IN; ++i) {
        int p = parent_indices[k * FAN_IN + i];
        int f;
        if (bytemode) f = (((const unsigned char*)prev_is_active)[p] != 0);
        else          f = (((const int*)prev_is_active)[p] != 0);
        cnt += f;
    }
    const bool active = (cnt >= THRESH);

    const size_t obase = (size_t)k * (NSP * NSP);
    if (half == 0 && tid == 0)
        out[(size_t)KN * NSP * NSP + k] = active ? 1.0f : 0.0f;

    if (!active) {
        float4 z = make_float4(0.f, 0.f, 0.f, 0.f);
        float4* o4 = (float4*)(out + obase + (size_t)half * 32 * NSP);
        #pragma unroll
        for (int i = tid; i < 32 * NSP / 4; i += 256) o4[i] = z;
        return;
    }

    float2 accs[4];
    #pragma unroll
    for (int s = 0; s < 4; ++s) accs[s] = make_float2(0.f, 0.f);

    const int  idxC = r0 * NSP + col;    // element index of (r0, col) within a map
    const bool rlo  = (r0 > 0);          // wave-uniform
    const bool rhi  = (r0 < 56);         // wave-uniform (r0+8 <= 63)
    const bool cl   = (col > 0);
    const bool cr   = (col < 63);

    for (int c = 0; c < FAN_IN; ++c) {
        const int p = parent_indices[k * FAN_IN + c];                 // s_load
        const float* __restrict__ src = prev_outputs + (size_t)p * (NSP * NSP);
        const float* wc = Wt + ((size_t)k * FAN_IN + c) * 9;          // s_load
        const float w00 = wc[0], w01 = wc[1], w02 = wc[2];
        const float w10 = wc[3], w11 = wc[4], w12 = wc[5];
        const float w20 = wc[6], w21 = wc[7], w22 = wc[8];

        // C[j].x = in[r0-1+j][col], C[j].y = in[r0+3+j][col], j=0..5
        float2 L[6], C[6], R[6];

        // center column (always in-bounds except halo rows)
        C[0].x = rlo ? src[idxC - NSP] : 0.0f;
        #pragma unroll
        for (int j = 1; j <= 5; ++j) C[j].x = src[idxC + (j - 1) * NSP];
        #pragma unroll
        for (int j = 0; j <= 4; ++j) C[j].y = src[idxC + (j + 3) * NSP];
        C[5].y = rhi ? src[idxC + 8 * NSP] : 0.0f;

        // left column (lane col==0 masked off -> no OOB access)
        if (cl) {
            L[0].x = rlo ? src[idxC - 1 - NSP] : 0.0f;
            #pragma unroll
            for (int j = 1; j <= 5; ++j) L[j].x = src[idxC - 1 + (j - 1) * NSP];
            #pragma unroll
            for (int j = 0; j <= 4; ++j) L[j].y = src[idxC - 1 + (j + 3) * NSP];
            L[5].y = rhi ? src[idxC - 1 + 8 * NSP] : 0.0f;
        } else {
            #pragma unroll
            for (int j = 0; j < 6; ++j) L[j] = make_float2(0.f, 0.f);
        }

        // right column (lane col==63 masked off)
        if (cr) {
            R[0].x = rlo ? src[idxC + 1 - NSP] : 0.0f;
            #pragma unroll
            for (int j = 1; j <= 5; ++j) R[j].x = src[idxC + 1 + (j - 1) * NSP];
            #pragma unroll
            for (int j = 0; j <= 4; ++j) R[j].y = src[idxC + 1 + (j + 3) * NSP];
            R[5].y = rhi ? src[idxC + 1 + 8 * NSP] : 0.0f;
        } else {
            #pragma unroll
            for (int j = 0; j < 6; ++j) R[j] = make_float2(0.f, 0.f);
        }

        // 36 packed FMAs: out rows (r0+s, r0+4+s), taps j = s..s+2
        #pragma unroll
        for (int s = 0; s < 4; ++s) {
            float2 a = accs[s];
            a = fma2(w00, L[s],     a);
            a = fma2(w01, C[s],     a);
            a = fma2(w02, R[s],     a);
            a = fma2(w10, L[s + 1], a);
            a = fma2(w11, C[s + 1], a);
            a = fma2(w12, R[s + 1], a);
            a = fma2(w20, L[s + 2], a);
            a = fma2(w21, C[s + 2], a);
            a = fma2(w22, R[s + 2], a);
            accs[s] = a;
        }
    }

    const float bk = bias[k];
    #pragma unroll
    for (int s = 0; s < 4; ++s) {
        out[obase + (size_t)(r0 + s)     * NSP + col] = tanh_fast(accs[s].x + bk);
        out[obase + (size_t)(r0 + 4 + s) * NSP + col] = tanh_fast(accs[s].y + bk);
    }
}

extern "C" void kernel_launch(void* const* d_in, const int* in_sizes, int n_in,
                              void* d_out, int out_size, void* d_ws, size_t ws_size,
                              hipStream_t stream) {
    const float* prev_outputs   = (const float*)d_in[0];
    const void*  prev_is_active = d_in[1];
    const int*   parent_indices = (const int*)d_in[2];
    const float* Wt             = (const float*)d_in[3];
    const float* bias           = (const float*)d_in[4];
    float*       out            = (float*)d_out;

    decoder_kernel<<<dim3(KN * 2), dim3(256), 0, stream>>>(
        prev_outputs, prev_is_active, parent_indices, Wt, bias, out);
}